// Round 1
// 610.349 us; speedup vs baseline: 1.1560x; 1.1560x over previous
//
#include <hip/hip_runtime.h>
#include <hip/hip_bf16.h>

#define B_  8
#define L_  200
#define D_  256
#define H_  8
#define HS_ 32
#define K_  20
#define BL_ 1600      // B*L
#define G_  64        // H*B
#define MW_ 7         // mask words per row: ceil(200/32)
#define NEG_INF (-3.402823466e38f)

__device__ __forceinline__ float bf2f(unsigned short u){
  return __uint_as_float(((unsigned int)u) << 16);
}
__device__ __forceinline__ unsigned short f2bf(float f){
  unsigned int x = __float_as_uint(f);
  unsigned int r = (x + 0x7fffu + ((x >> 16) & 1u)) >> 16;  // RNE
  return (unsigned short)r;
}
__device__ __forceinline__ void up2(unsigned int u, float& lo, float& hi){
  lo = __uint_as_float(u << 16);
  hi = __uint_as_float(u & 0xffff0000u);
}

// Uniform-flag dtype accessors (fp/mk are wave-uniform -> no divergence cost)
__device__ __forceinline__ float loadf(const void* base, size_t i, int fp){
  return fp ? ((const float*)base)[i] : bf2f(((const unsigned short*)base)[i]);
}
__device__ __forceinline__ void load8f(const void* base, size_t i, int fp, float f[8]){
  if (fp){
    const float4* p = (const float4*)((const float*)base + i);
    float4 x = p[0], y = p[1];
    f[0]=x.x; f[1]=x.y; f[2]=x.z; f[3]=x.w; f[4]=y.x; f[5]=y.y; f[6]=y.z; f[7]=y.w;
  } else {
    uint4 v = *(const uint4*)((const unsigned short*)base + i);
    up2(v.x,f[0],f[1]); up2(v.y,f[2],f[3]); up2(v.z,f[4],f[5]); up2(v.w,f[6],f[7]);
  }
}
__device__ __forceinline__ int mask_at(const void* am, int i, int mk){
  switch(mk){
    case 0:  return ((const int*)am)[i] != 0;            // int32 bool
    case 1:  return ((const unsigned char*)am)[i] != 0;  // byte bool
    case 2:  return ((const unsigned int*)am)[i] != 0;   // fp32 bool (0 / 1.0f)
    default: return ((const unsigned short*)am)[i] != 0; // bf16 bool
  }
}
__device__ __forceinline__ void storef(void* base, size_t i, int fp, float v){
  if (fp) ((float*)base)[i] = v; else ((unsigned short*)base)[i] = f2bf(v);
}

// ---------------- Kernel D: detect wire dtypes. flags[0]=float_is_fp32, flags[1]=mask kind
__global__ __launch_bounds__(256) void k_detect(
    const unsigned short* __restrict__ seqs, const unsigned int* __restrict__ am,
    int* __restrict__ flags)
{
  int t = threadIdx.x;
  __shared__ int r[5];   // bad_bf16, v_i32, v_byte, v_f32ambig, v_bf16
  if (t < 5) r[t] = 0;
  __syncthreads();

  int bad = 0;
  for (int i = t; i < 4096; i += 256){
    unsigned e = (seqs[i] >> 7) & 0xFFu;
    if (e >= 160u) bad++;   // |x| >= 2^33: impossible for bf16 N(0,1) data
  }
  int vi = 0, vb = 0, vf = 0, vh = 0;
  for (int i = t; i < 1024; i += 256){
    unsigned w = am[i];
    if (w == 0u) continue;
    if (w == 1u) vi++;
    else if (w == 0x3F800000u) vf++;                       // fp32 1.0 OR bf16 pair (0,1)
    else if (w == 0x00003F80u || w == 0x3F803F80u) vh++;   // bf16 bool pairs
    else if ((w & 0xFEFEFEFEu) == 0u) vb++;                // packed bytes in {0,1}
    else vb++;
  }
  atomicAdd(&r[0], bad); atomicAdd(&r[1], vi); atomicAdd(&r[2], vb);
  atomicAdd(&r[3], vf);  atomicAdd(&r[4], vh);
  __syncthreads();
  if (t == 0){
    flags[0] = (r[0] > 32) ? 1 : 0;
    int kind;
    if (r[2] > r[1] && r[2] > r[3] + r[4]) kind = 1;       // byte
    else if (r[4] > 0)                     kind = 3;       // bf16
    else if (r[3] > r[1])                  kind = 2;       // fp32
    else                                   kind = 0;       // int32
    flags[1] = kind;
  }
}

// ---------------- Kernel 0: zero mask words (capture-safe)
__global__ __launch_bounds__(256) void kz_zero(unsigned int* __restrict__ p, int n){
  int i = blockIdx.x * 256 + threadIdx.x;
  if (i < n) p[i] = 0u;
}

// ---------------- Kernel 1: a_ = seqs@W1^T+b1, b_ = seqs@W2^T+b2, seqs_h = seqs@Ww^T+bw
__global__ __launch_bounds__(256) void k1_linear(
    const void* __restrict__ seqs,
    const void* __restrict__ w1, const void* __restrict__ b1,
    const void* __restrict__ w2, const void* __restrict__ b2,
    const void* __restrict__ w3, const void* __restrict__ b3,
    const int* __restrict__ flags,
    float* __restrict__ da, float* __restrict__ db, float* __restrict__ dsh)
{
  int fp = flags[0];
  int bid = blockIdx.x;
  int m  = bid / 400;
  int rb = (bid % 400) * 4;
  const void* w; const void* bias; float* dst;
  if (m == 0)      { w = w1; bias = b1; dst = da;  }
  else if (m == 1) { w = w2; bias = b2; dst = db;  }
  else             { w = w3; bias = b3; dst = dsh; }

  __shared__ float s4[4][D_];
  int t = threadIdx.x;
  for (int l = t; l < 4 * D_; l += 256){
    int rr = l >> 8, c = l & 255;
    s4[rr][c] = loadf(seqs, (size_t)(rb + rr) * D_ + c, fp);
  }
  __syncthreads();

  float acc[4];
  float bv = loadf(bias, t, fp);
  #pragma unroll
  for (int rr = 0; rr < 4; rr++) acc[rr] = bv;

  for (int c8 = 0; c8 < 32; c8++){
    float wf[8];
    load8f(w, (size_t)t * D_ + c8 * 8, fp, wf);
    #pragma unroll
    for (int rr = 0; rr < 4; rr++){
      const float* sf = &s4[rr][c8 * 8];
      #pragma unroll
      for (int i = 0; i < 8; i++) acc[rr] += sf[i] * wf[i];
    }
  }
  #pragma unroll
  for (int rr = 0; rr < 4; rr++)
    dst[(size_t)(rb + rr) * D_ + t] = acc[rr];
}

// ---------------- Kernel 2 (rewritten): coalesced raw row compute + top-K + symmetric bitmask
// Thread t: row k = k0 + (t>>5), columns c0=(t&31)*8 .. c0+7 (head h = (t&31)>>2).
// A wave's 64 lanes read 1024 contiguous bytes of tm -> fully coalesced.
// b_ read straight from global (L2-resident, 204.8KB/batch reused by 200 blocks).
// No LDS staging, no barriers in the main loop. Per-head reduce = 2x shfl_xor.
__global__ __launch_bounds__(256) void k2_rawtopk(
    const float* __restrict__ a_, const float* __restrict__ b_,
    const void* __restrict__ tm, const void* __restrict__ am,
    const int* __restrict__ flags, unsigned int* __restrict__ maskw,
    float* __restrict__ rawg)
{
  int fp = flags[0], mk = flags[1];
  int bid = blockIdx.x;
  int bb = bid / L_;
  int q  = bid - bb * L_;
  int t = threadIdx.x;
  int rsub = t >> 5;        // row-within-chunk 0..7
  int cg   = t & 31;        // column group
  int c0   = cg * 8;        // starting column
  int h    = cg >> 2;       // head of this thread's 8 columns

  __shared__ float raw_sh[8 * 208];   // [h][k]

  // a values for this thread's 8 columns (coalesced 32B/lane)
  float areg[8];
  const float* arow = a_ + (size_t)(bb * L_ + q) * D_;
  {
    const float4* a4 = (const float4*)(arow + c0);
    float4 x = a4[0], y = a4[1];
    areg[0]=x.x; areg[1]=x.y; areg[2]=x.z; areg[3]=x.w;
    areg[4]=y.x; areg[5]=y.y; areg[6]=y.z; areg[7]=y.w;
  }
  // a2 for this head: butterfly over the 4-lane column group (xor 1, 2)
  float a2;
  {
    float s = 0.f;
    #pragma unroll
    for (int e = 0; e < 8; e++) s += areg[e] * areg[e];
    s += __shfl_xor(s, 1);
    s += __shfl_xor(s, 2);
    a2 = sqrtf(s);
  }

  const size_t tmbase = (size_t)(bb * L_ + q) * L_ * D_;
  const float* bbase  = b_ + (size_t)bb * L_ * D_;
  const int amrow = q * L_;

  for (int k0 = 0; k0 < L_; k0 += 8){
    int k = k0 + rsub;                       // < 200 always (192+7)
    float tf[8];
    load8f(tm, tmbase + (size_t)k * D_ + c0, fp, tf);
    const float4* b4 = (const float4*)(bbase + (size_t)k * D_ + c0);
    float4 bv0 = b4[0], bv1 = b4[1];
    float bf[8] = {bv0.x, bv0.y, bv0.z, bv0.w, bv1.x, bv1.y, bv1.z, bv1.w};
    float p1 = 0.f, p2 = 0.f;
    #pragma unroll
    for (int i = 0; i < 8; i++){
      float sv = bf[i] + tf[i];
      p1 += areg[i] * sv;
      p2 += sv * sv;
    }
    p1 += __shfl_xor(p1, 1); p2 += __shfl_xor(p2, 1);
    p1 += __shfl_xor(p1, 2); p2 += __shfl_xor(p2, 2);
    if ((cg & 3) == 0){
      float r = p1 / (a2 * sqrtf(p2) + 1e-6f);
      if (mask_at(am, amrow + k, mk)) r = 0.f;
      raw_sh[h * 208 + k] = r;
    }
  }
  __syncthreads();

  // Optional: persist raw graph for k3's gather path (coalesced 800B rows)
  if (rawg){
    #pragma unroll
    for (int hh2 = 0; hh2 < 8; hh2++){
      if (t < L_)
        rawg[((size_t)(hh2 * B_ + bb) * L_ + q) * L_ + t] = raw_sh[hh2 * 208 + t];
    }
  }

  // top-K + symmetric bitmask (unchanged)
  int wv = t >> 6, lane = t & 63;
  for (int hh = 2 * wv; hh <= 2 * wv + 1; hh++){
    const float* r = &raw_sh[hh * 208];
    int g = hh * B_ + bb;

    float v0 = (lane       < L_) ? r[lane]       : NEG_INF;
    float v1 = (lane + 64  < L_) ? r[lane + 64]  : NEG_INF;
    float v2 = (lane + 128 < L_) ? r[lane + 128] : NEG_INF;
    float v3 = (lane + 192 < L_) ? r[lane + 192] : NEG_INF;

    for (int it = 0; it < K_; it++){
      float bv = v0; int bi = lane;
      if (v1 > bv){ bv = v1; bi = lane + 64;  }
      if (v2 > bv){ bv = v2; bi = lane + 128; }
      if (v3 > bv){ bv = v3; bi = lane + 192; }
      #pragma unroll
      for (int off = 1; off < 64; off <<= 1){
        float ov = __shfl_xor(bv, off);
        int   oi = __shfl_xor(bi, off);
        if (ov > bv || (ov == bv && oi < bi)){ bv = ov; bi = oi; }
      }
      if (bi == lane)            v0 = NEG_INF;
      else if (bi == lane + 64)  v1 = NEG_INF;
      else if (bi == lane + 128) v2 = NEG_INF;
      else if (bi == lane + 192) v3 = NEG_INF;
      if (lane == 0){
        atomicOr(&maskw[((size_t)g * L_ + q)  * MW_ + (bi >> 5)], 1u << (bi & 31));
        atomicOr(&maskw[((size_t)g * L_ + bi) * MW_ + (q  >> 5)], 1u << (q  & 31));
      }
    }
  }
}

// ---------------- Kernel 3: compact columns, gather (or recompute) values, sparse matvec,
// time_outputs + fused LayerNorm. Output dtype follows detected float wire.
__global__ __launch_bounds__(256) void k3_gatherln(
    const float* __restrict__ a_, const float* __restrict__ b_,
    const float* __restrict__ sh_, const void* __restrict__ tm,
    const void* __restrict__ am, const unsigned int* __restrict__ maskw,
    const void* __restrict__ gamma, const void* __restrict__ beta,
    const int* __restrict__ flags, const float* __restrict__ rawg,
    void* __restrict__ out)
{
  int fp = flags[0], mk = flags[1];
  int bid = blockIdx.x;
  int bb = bid / L_;
  int q  = bid - bb * L_;
  int t = threadIdx.x;

  __shared__ float a_sh[D_];
  __shared__ float s_a2[8];
  __shared__ int   s_k[8][200];
  __shared__ float s_v[8][200];
  __shared__ int   s_cnt[8];
  __shared__ float red[8];

  a_sh[t] = a_[(size_t)(bb * L_ + q) * D_ + t];
  __syncthreads();
  if (t < 8){
    float s = 0.f;
    #pragma unroll
    for (int e = 0; e < HS_; e++){ float d = a_sh[t * HS_ + e]; s += d * d; }
    s_a2[t] = sqrtf(s);
  }
  __syncthreads();

  int wv = t >> 6, lane = t & 63;
  for (int hh = 2 * wv; hh <= 2 * wv + 1; hh++){
    int g = hh * B_ + bb;
    const unsigned int* mrow = &maskw[((size_t)g * L_ + q) * MW_];
    int cnt = 0;
    #pragma unroll
    for (int c = 0; c < 4; c++){
      int k = c * 64 + lane;
      bool sel = (k < L_) && ((mrow[k >> 5] >> (k & 31)) & 1u) && !mask_at(am, q * L_ + k, mk);
      unsigned long long bal = __ballot(sel);
      int pos = __popcll(bal & ((1ull << lane) - 1ull));
      if (sel) s_k[hh][cnt + pos] = k;
      cnt += __popcll(bal);
    }
    if (lane == 0) s_cnt[hh] = cnt;

    if (rawg){
      // gather precomputed raw values (bitwise identical to recompute)
      const float* rrow = rawg + ((size_t)g * L_ + q) * L_;
      for (int i = lane; i < cnt; i += 64)
        s_v[hh][i] = rrow[s_k[hh][i]];
    } else {
      float a2 = s_a2[hh];
      for (int i = lane; i < cnt; i += 64){
        int k = s_k[hh][i];
        size_t pbase = ((size_t)(bb * L_ + q) * L_ + k) * D_ + hh * HS_;
        const float4* b4 = (const float4*)(b_ + (size_t)(bb * L_ + k) * D_ + hh * HS_);
        float p1 = 0.f, p2 = 0.f;
        #pragma unroll
        for (int e8 = 0; e8 < 4; e8++){
          float tf[8];
          load8f(tm, pbase + e8 * 8, fp, tf);
          float4 bv0 = b4[e8 * 2], bv1 = b4[e8 * 2 + 1];
          float bf[8] = {bv0.x, bv0.y, bv0.z, bv0.w, bv1.x, bv1.y, bv1.z, bv1.w};
          #pragma unroll
          for (int i2 = 0; i2 < 8; i2++){
            float s = bf[i2] + tf[i2];
            p1 += a_sh[hh * HS_ + e8 * 8 + i2] * s;
            p2 += s * s;
          }
        }
        s_v[hh][i] = p1 / (a2 * sqrtf(p2) + 1e-6f);
      }
    }
  }
  __syncthreads();

  int h = t >> 5, hs = t & 31;
  int cnt = s_cnt[h];
  float acc_o = 0.f, acc_t = 0.f;
  const size_t tmrow = (size_t)(bb * L_ + q) * L_ * D_;
  for (int i = 0; i < cnt; i++){
    int k = s_k[h][i];
    float v = s_v[h][i];
    acc_o += v * sh_[(size_t)(bb * L_ + k) * D_ + h * HS_ + hs];
    acc_t += v * loadf(tm, tmrow + (size_t)k * D_ + h * HS_ + hs, fp);
  }
  size_t orow = (size_t)(bb * L_ + q) * D_;
  storef(out, (size_t)409600 + orow + t, fp, acc_t);

  float s = acc_o;
  #pragma unroll
  for (int off = 1; off < 64; off <<= 1) s += __shfl_xor(s, off);
  if (lane == 0) red[wv] = s;
  __syncthreads();
  float mean = (red[0] + red[1] + red[2] + red[3]) * (1.f / 256.f);

  float d = acc_o - mean;
  float s2 = d * d;
  #pragma unroll
  for (int off = 1; off < 64; off <<= 1) s2 += __shfl_xor(s2, off);
  if (lane == 0) red[4 + wv] = s2;
  __syncthreads();
  float var = (red[4] + red[5] + red[6] + red[7]) * (1.f / 256.f);

  float y = d * (1.f / sqrtf(var + 1e-8f)) * loadf(gamma, t, fp) + loadf(beta, t, fp);
  storef(out, orow + t, fp, y);
}

extern "C" void kernel_launch(void* const* d_in, const int* in_sizes, int n_in,
                              void* d_out, int out_size, void* d_ws, size_t ws_size,
                              hipStream_t stream) {
  const void* seqs = d_in[0];
  const void* am   = d_in[1];
  const void* tm   = d_in[2];
  const void* w1   = d_in[3];
  const void* b1   = d_in[4];
  const void* w2   = d_in[5];
  const void* b2   = d_in[6];
  const void* w3   = d_in[7];
  const void* b3   = d_in[8];
  const void* lng  = d_in[9];
  const void* lnb  = d_in[10];

  float* ws = (float*)d_ws;
  int*   flags = (int*)ws;                              // 16 ints (64 B)
  float* a_    = ws + 16;                               // 409600 f32
  float* b_    = ws + 16 + 409600;                      // 409600 f32
  float* sh_   = ws + 16 + 819200;                      // 409600 f32
  unsigned int* maskw = (unsigned int*)(ws + 16 + 1228800);  // 89600 u32
  float* rawg  = ws + 16 + 1228800 + 89600;             // 2,560,000 f32 (10.24 MB, optional)
  size_t need  = ((size_t)16 + 1228800 + 89600 + 2560000) * 4;  // ~15.5 MB
  float* rawg_arg = (ws_size >= need) ? rawg : nullptr;

  k_detect   <<<1,   256, 0, stream>>>((const unsigned short*)seqs, (const unsigned int*)am, flags);
  kz_zero    <<<350, 256, 0, stream>>>(maskw, G_ * L_ * MW_);
  k1_linear  <<<1200, 256, 0, stream>>>(seqs, w1, b1, w2, b2, w3, b3, flags, a_, b_, sh_);
  k2_rawtopk <<<BL_, 256, 0, stream>>>(a_, b_, tm, am, flags, maskw, rawg_arg);
  k3_gatherln<<<BL_, 256, 0, stream>>>(a_, b_, sh_, tm, am, maskw, lng, lnb, flags, rawg_arg, d_out);
}

// Round 2
// 586.648 us; speedup vs baseline: 1.2027x; 1.0404x over previous
//
#include <hip/hip_runtime.h>
#include <hip/hip_bf16.h>

#define B_  8
#define L_  200
#define D_  256
#define H_  8
#define HS_ 32
#define K_  20
#define BL_ 1600      // B*L
#define G_  64        // H*B
#define MW_ 7         // mask words per row: ceil(200/32)
#define NEG_INF (-3.402823466e38f)

__device__ __forceinline__ float bf2f(unsigned short u){
  return __uint_as_float(((unsigned int)u) << 16);
}
__device__ __forceinline__ unsigned short f2bf(float f){
  unsigned int x = __float_as_uint(f);
  unsigned int r = (x + 0x7fffu + ((x >> 16) & 1u)) >> 16;  // RNE
  return (unsigned short)r;
}
__device__ __forceinline__ void up2(unsigned int u, float& lo, float& hi){
  lo = __uint_as_float(u << 16);
  hi = __uint_as_float(u & 0xffff0000u);
}

// Uniform-flag dtype accessors (fp/mk are wave-uniform -> no divergence cost)
__device__ __forceinline__ float loadf(const void* base, size_t i, int fp){
  return fp ? ((const float*)base)[i] : bf2f(((const unsigned short*)base)[i]);
}
__device__ __forceinline__ void load8f(const void* base, size_t i, int fp, float f[8]){
  if (fp){
    const float4* p = (const float4*)((const float*)base + i);
    float4 x = p[0], y = p[1];
    f[0]=x.x; f[1]=x.y; f[2]=x.z; f[3]=x.w; f[4]=y.x; f[5]=y.y; f[6]=y.z; f[7]=y.w;
  } else {
    uint4 v = *(const uint4*)((const unsigned short*)base + i);
    up2(v.x,f[0],f[1]); up2(v.y,f[2],f[3]); up2(v.z,f[4],f[5]); up2(v.w,f[6],f[7]);
  }
}
__device__ __forceinline__ int mask_at(const void* am, int i, int mk){
  switch(mk){
    case 0:  return ((const int*)am)[i] != 0;            // int32 bool
    case 1:  return ((const unsigned char*)am)[i] != 0;  // byte bool
    case 2:  return ((const unsigned int*)am)[i] != 0;   // fp32 bool (0 / 1.0f)
    default: return ((const unsigned short*)am)[i] != 0; // bf16 bool
  }
}
__device__ __forceinline__ void storef(void* base, size_t i, int fp, float v){
  if (fp) ((float*)base)[i] = v; else ((unsigned short*)base)[i] = f2bf(v);
}

// ---------------- Kernel 0: zero mask words (blocks 0..349) + dtype detect (block 350)
__global__ __launch_bounds__(256) void k0_init(
    const unsigned short* __restrict__ seqs, const unsigned int* __restrict__ am,
    int* __restrict__ flags, unsigned int* __restrict__ maskw)
{
  int t = threadIdx.x;
  int i = blockIdx.x * 256 + t;
  if (i < G_ * L_ * MW_) maskw[i] = 0u;

  if (blockIdx.x == 350){
    __shared__ int r[5];   // bad_bf16, v_i32, v_byte, v_f32ambig, v_bf16
    if (t < 5) r[t] = 0;
    __syncthreads();

    int bad = 0;
    for (int j = t; j < 4096; j += 256){
      unsigned e = (seqs[j] >> 7) & 0xFFu;
      if (e >= 160u) bad++;   // |x| >= 2^33: impossible for bf16 N(0,1) data
    }
    int vi = 0, vb = 0, vf = 0, vh = 0;
    for (int j = t; j < 1024; j += 256){
      unsigned w = am[j];
      if (w == 0u) continue;
      if (w == 1u) vi++;
      else if (w == 0x3F800000u) vf++;                       // fp32 1.0 OR bf16 pair (0,1)
      else if (w == 0x00003F80u || w == 0x3F803F80u) vh++;   // bf16 bool pairs
      else if ((w & 0xFEFEFEFEu) == 0u) vb++;                // packed bytes in {0,1}
      else vb++;
    }
    atomicAdd(&r[0], bad); atomicAdd(&r[1], vi); atomicAdd(&r[2], vb);
    atomicAdd(&r[3], vf);  atomicAdd(&r[4], vh);
    __syncthreads();
    if (t == 0){
      flags[0] = (r[0] > 32) ? 1 : 0;
      int kind;
      if (r[2] > r[1] && r[2] > r[3] + r[4]) kind = 1;       // byte
      else if (r[4] > 0)                     kind = 3;       // bf16
      else if (r[3] > r[1])                  kind = 2;       // fp32
      else                                   kind = 0;       // int32
      flags[1] = kind;
    }
  }
}

// ---------------- Kernel 1: a_ = seqs@W1^T+b1, b_ = seqs@W2^T+b2, seqs_h = seqs@Ww^T+bw
__global__ __launch_bounds__(256) void k1_linear(
    const void* __restrict__ seqs,
    const void* __restrict__ w1, const void* __restrict__ b1,
    const void* __restrict__ w2, const void* __restrict__ b2,
    const void* __restrict__ w3, const void* __restrict__ b3,
    const int* __restrict__ flags,
    float* __restrict__ da, float* __restrict__ db, float* __restrict__ dsh)
{
  int fp = flags[0];
  int bid = blockIdx.x;
  int m  = bid / 400;
  int rb = (bid % 400) * 4;
  const void* w; const void* bias; float* dst;
  if (m == 0)      { w = w1; bias = b1; dst = da;  }
  else if (m == 1) { w = w2; bias = b2; dst = db;  }
  else             { w = w3; bias = b3; dst = dsh; }

  __shared__ float s4[4][D_];
  int t = threadIdx.x;
  for (int l = t; l < 4 * D_; l += 256){
    int rr = l >> 8, c = l & 255;
    s4[rr][c] = loadf(seqs, (size_t)(rb + rr) * D_ + c, fp);
  }
  __syncthreads();

  float acc[4];
  float bv = loadf(bias, t, fp);
  #pragma unroll
  for (int rr = 0; rr < 4; rr++) acc[rr] = bv;

  for (int c8 = 0; c8 < 32; c8++){
    float wf[8];
    load8f(w, (size_t)t * D_ + c8 * 8, fp, wf);
    #pragma unroll
    for (int rr = 0; rr < 4; rr++){
      const float* sf = &s4[rr][c8 * 8];
      #pragma unroll
      for (int i = 0; i < 8; i++) acc[rr] += sf[i] * wf[i];
    }
  }
  #pragma unroll
  for (int rr = 0; rr < 4; rr++)
    dst[(size_t)(rb + rr) * D_ + t] = acc[rr];
}

// ---------------- Kernel 2a: pure streaming raw-graph compute.
// Thread t: row k = k0 + (t>>5), columns c0=(t&31)*8 (head h = (t&31)>>2).
// Wave reads 1024B contiguous of tm -> fully coalesced. b_ straight from L2.
// No barriers in the main loop; no top-K tail. Output: rawg rows (800B coalesced).
__global__ __launch_bounds__(256) void k2a_raw(
    const float* __restrict__ a_, const float* __restrict__ b_,
    const void* __restrict__ tm, const void* __restrict__ am,
    const int* __restrict__ flags, float* __restrict__ rawg)
{
  int fp = flags[0], mk = flags[1];
  int bid = blockIdx.x;
  int bb = bid / L_;
  int q  = bid - bb * L_;
  int t = threadIdx.x;
  int rsub = t >> 5;        // row-within-chunk 0..7
  int cg   = t & 31;        // column group
  int c0   = cg * 8;        // starting column
  int h    = cg >> 2;       // head of this thread's 8 columns

  __shared__ float raw_sh[8 * 208];   // [h][k]

  // a values for this thread's 8 columns (coalesced 32B/lane)
  float areg[8];
  const float* arow = a_ + (size_t)(bb * L_ + q) * D_;
  {
    const float4* a4 = (const float4*)(arow + c0);
    float4 x = a4[0], y = a4[1];
    areg[0]=x.x; areg[1]=x.y; areg[2]=x.z; areg[3]=x.w;
    areg[4]=y.x; areg[5]=y.y; areg[6]=y.z; areg[7]=y.w;
  }
  // a2 for this head: butterfly over the 4-lane column group (xor 1, 2)
  float a2;
  {
    float s = 0.f;
    #pragma unroll
    for (int e = 0; e < 8; e++) s += areg[e] * areg[e];
    s += __shfl_xor(s, 1);
    s += __shfl_xor(s, 2);
    a2 = sqrtf(s);
  }

  const size_t tmbase = (size_t)(bb * L_ + q) * L_ * D_;
  const float* bbase  = b_ + (size_t)bb * L_ * D_;
  const int amrow = q * L_;

  #pragma unroll 2
  for (int k0 = 0; k0 < L_; k0 += 8){
    int k = k0 + rsub;                       // < 200 always (192+7)
    float tf[8];
    load8f(tm, tmbase + (size_t)k * D_ + c0, fp, tf);
    const float4* b4 = (const float4*)(bbase + (size_t)k * D_ + c0);
    float4 bv0 = b4[0], bv1 = b4[1];
    float bf[8] = {bv0.x, bv0.y, bv0.z, bv0.w, bv1.x, bv1.y, bv1.z, bv1.w};
    float p1 = 0.f, p2 = 0.f;
    #pragma unroll
    for (int i = 0; i < 8; i++){
      float sv = bf[i] + tf[i];
      p1 += areg[i] * sv;
      p2 += sv * sv;
    }
    p1 += __shfl_xor(p1, 1); p2 += __shfl_xor(p2, 1);
    p1 += __shfl_xor(p1, 2); p2 += __shfl_xor(p2, 2);
    if ((cg & 3) == 0){
      float r = p1 / (a2 * sqrtf(p2) + 1e-6f);
      if (mask_at(am, amrow + k, mk)) r = 0.f;
      raw_sh[h * 208 + k] = r;
    }
  }
  __syncthreads();

  // Persist raw graph (coalesced 800B rows), consumed by k2b (top-K) and k3 (gather)
  #pragma unroll
  for (int hh2 = 0; hh2 < 8; hh2++){
    if (t < L_)
      rawg[((size_t)(hh2 * B_ + bb) * L_ + q) * L_ + t] = raw_sh[hh2 * 208 + t];
  }
}

// ---------------- Kernel 2b: top-K per row + symmetric bitmask. One wave per (g,q) row.
__global__ __launch_bounds__(256) void k2b_topk(
    const float* __restrict__ rawg, unsigned int* __restrict__ maskw)
{
  int wv = threadIdx.x >> 6, lane = threadIdx.x & 63;
  int row = blockIdx.x * 4 + wv;           // row = g*L + q, grid = 12800/4 = 3200
  int g = row / L_;
  int q = row - g * L_;
  const float* r = rawg + (size_t)row * L_;

  float v0 = r[lane];
  float v1 = r[lane + 64];
  float v2 = (lane + 128 < L_) ? r[lane + 128] : NEG_INF;
  float v3 = (lane + 192 < L_) ? r[lane + 192] : NEG_INF;

  for (int it = 0; it < K_; it++){
    float bv = v0; int bi = lane;
    if (v1 > bv){ bv = v1; bi = lane + 64;  }
    if (v2 > bv){ bv = v2; bi = lane + 128; }
    if (v3 > bv){ bv = v3; bi = lane + 192; }
    #pragma unroll
    for (int off = 1; off < 64; off <<= 1){
      float ov = __shfl_xor(bv, off);
      int   oi = __shfl_xor(bi, off);
      if (ov > bv || (ov == bv && oi < bi)){ bv = ov; bi = oi; }
    }
    if (bi == lane)            v0 = NEG_INF;
    else if (bi == lane + 64)  v1 = NEG_INF;
    else if (bi == lane + 128) v2 = NEG_INF;
    else if (bi == lane + 192) v3 = NEG_INF;
    if (lane == 0){
      atomicOr(&maskw[((size_t)g * L_ + q)  * MW_ + (bi >> 5)], 1u << (bi & 31));
      atomicOr(&maskw[((size_t)g * L_ + bi) * MW_ + (q  >> 5)], 1u << (q  & 31));
    }
  }
}

// ---------------- Kernel 3: compact columns, gather values from rawg, sparse matvec,
// time_outputs + fused LayerNorm. Output dtype follows detected float wire.
__global__ __launch_bounds__(256) void k3_gatherln(
    const float* __restrict__ sh_, const void* __restrict__ tm,
    const void* __restrict__ am, const unsigned int* __restrict__ maskw,
    const float* __restrict__ rawg,
    const void* __restrict__ gamma, const void* __restrict__ beta,
    const int* __restrict__ flags, void* __restrict__ out)
{
  int fp = flags[0], mk = flags[1];
  int bid = blockIdx.x;
  int bb = bid / L_;
  int q  = bid - bb * L_;
  int t = threadIdx.x;

  __shared__ int   s_k[8][200];
  __shared__ float s_v[8][200];
  __shared__ int   s_cnt[8];
  __shared__ float red[8];

  int wv = t >> 6, lane = t & 63;
  for (int hh = 2 * wv; hh <= 2 * wv + 1; hh++){
    int g = hh * B_ + bb;
    const unsigned int* mrow = &maskw[((size_t)g * L_ + q) * MW_];
    int cnt = 0;
    #pragma unroll
    for (int c = 0; c < 4; c++){
      int k = c * 64 + lane;
      bool sel = (k < L_) && ((mrow[k >> 5] >> (k & 31)) & 1u) && !mask_at(am, q * L_ + k, mk);
      unsigned long long bal = __ballot(sel);
      int pos = __popcll(bal & ((1ull << lane) - 1ull));
      if (sel) s_k[hh][cnt + pos] = k;
      cnt += __popcll(bal);
    }
    if (lane == 0) s_cnt[hh] = cnt;

    // gather precomputed raw values (bitwise identical to recompute)
    const float* rrow = rawg + ((size_t)g * L_ + q) * L_;
    for (int i = lane; i < cnt; i += 64)
      s_v[hh][i] = rrow[s_k[hh][i]];
  }
  __syncthreads();

  int h = t >> 5, hs = t & 31;
  int hb = h * HS_ + hs;
  int cnt = s_cnt[h];
  const size_t tmrow = (size_t)(bb * L_ + q) * L_ * D_;
  const float* shb = sh_ + (size_t)bb * L_ * D_;

  float acc_o = 0.f, acc_t = 0.f, acc_o1 = 0.f, acc_t1 = 0.f;
  int i = 0;
  for (; i + 2 <= cnt; i += 2){
    int ka = s_k[h][i], kb = s_k[h][i + 1];
    float va = s_v[h][i], vb = s_v[h][i + 1];
    float soa = shb[(size_t)ka * D_ + hb];
    float sob = shb[(size_t)kb * D_ + hb];
    float sta = loadf(tm, tmrow + (size_t)ka * D_ + hb, fp);
    float stb = loadf(tm, tmrow + (size_t)kb * D_ + hb, fp);
    acc_o  += va * soa;  acc_t  += va * sta;
    acc_o1 += vb * sob;  acc_t1 += vb * stb;
  }
  if (i < cnt){
    int ka = s_k[h][i];
    float va = s_v[h][i];
    acc_o += va * shb[(size_t)ka * D_ + hb];
    acc_t += va * loadf(tm, tmrow + (size_t)ka * D_ + hb, fp);
  }
  acc_o += acc_o1;  acc_t += acc_t1;

  size_t orow = (size_t)(bb * L_ + q) * D_;
  storef(out, (size_t)409600 + orow + t, fp, acc_t);

  float s = acc_o;
  #pragma unroll
  for (int off = 1; off < 64; off <<= 1) s += __shfl_xor(s, off);
  if (lane == 0) red[wv] = s;
  __syncthreads();
  float mean = (red[0] + red[1] + red[2] + red[3]) * (1.f / 256.f);

  float d = acc_o - mean;
  float s2 = d * d;
  #pragma unroll
  for (int off = 1; off < 64; off <<= 1) s2 += __shfl_xor(s2, off);
  if (lane == 0) red[4 + wv] = s2;
  __syncthreads();
  float var = (red[4] + red[5] + red[6] + red[7]) * (1.f / 256.f);

  float y = d * (1.f / sqrtf(var + 1e-8f)) * loadf(gamma, t, fp) + loadf(beta, t, fp);
  storef(out, orow + t, fp, y);
}

extern "C" void kernel_launch(void* const* d_in, const int* in_sizes, int n_in,
                              void* d_out, int out_size, void* d_ws, size_t ws_size,
                              hipStream_t stream) {
  const void* seqs = d_in[0];
  const void* am   = d_in[1];
  const void* tm   = d_in[2];
  const void* w1   = d_in[3];
  const void* b1   = d_in[4];
  const void* w2   = d_in[5];
  const void* b2   = d_in[6];
  const void* w3   = d_in[7];
  const void* b3   = d_in[8];
  const void* lng  = d_in[9];
  const void* lnb  = d_in[10];

  float* ws = (float*)d_ws;
  int*   flags = (int*)ws;                              // 16 ints (64 B)
  float* a_    = ws + 16;                               // 409600 f32
  float* b_    = ws + 16 + 409600;                      // 409600 f32
  float* sh_   = ws + 16 + 819200;                      // 409600 f32
  unsigned int* maskw = (unsigned int*)(ws + 16 + 1228800);  // 89600 u32
  float* rawg  = ws + 16 + 1228800 + 89600;             // 2,560,000 f32 (10.24 MB)
  // total ws use ~15.5 MB (allocation observed at 1.31 GB)

  k0_init    <<<351,  256, 0, stream>>>((const unsigned short*)seqs, (const unsigned int*)am, flags, maskw);
  k1_linear  <<<1200, 256, 0, stream>>>(seqs, w1, b1, w2, b2, w3, b3, flags, a_, b_, sh_);
  k2a_raw    <<<BL_,  256, 0, stream>>>(a_, b_, tm, am, flags, rawg);
  k2b_topk   <<<3200, 256, 0, stream>>>(rawg, maskw);
  k3_gatherln<<<BL_,  256, 0, stream>>>(sh_, tm, am, maskw, rawg, lng, lnb, flags, d_out);
}